// Round 6
// baseline (280.490 us; speedup 1.0000x reference)
//
#include <hip/hip_runtime.h>
#include <hip/hip_bf16.h>
#include <math.h>

#define NP 512
#define NW 3584
#define NT 4096
#define FIN 256
#define H1 8
#define O1 32
#define H2 8
#define O2 256
#define NEG 0.2f

typedef __attribute__((ext_vector_type(8))) short bf16x8;
typedef __attribute__((ext_vector_type(4))) float f32x4;
typedef __attribute__((ext_vector_type(2))) float v2f;
typedef __attribute__((ext_vector_type(16))) unsigned int u32x16;
typedef unsigned long long u64;

__device__ __forceinline__ unsigned short f2bf(float f) {
    unsigned u = __float_as_uint(f);
    unsigned r = (u + 0x7FFF + ((u >> 16) & 1)) >> 16;
    return (unsigned short)r;
}

__device__ __forceinline__ float fast_tanh(float x) {
    float ex = __expf(2.0f * x);
    return 1.0f - 2.0f / (ex + 1.0f);   // saturates to +-1
}

// ===== fused prep: conv_word | gat1_hp | conv_w2(transpose) | pack_adj(n-lane T) | cvec
// grid = 896 + 256 + 128 + 896 + 1 = 2177 blocks of 256
__global__ __launch_bounds__(256) void k_prep(
    const float* __restrict__ wf, const float* __restrict__ pf,
    const float* __restrict__ w1, const float* __restrict__ a_src1,
    const float* __restrict__ a_dst1, const float* __restrict__ w2,
    const float* __restrict__ b2, const float* __restrict__ W_fc,
    const int* __restrict__ wp_adj,
    unsigned short* __restrict__ abf, unsigned short* __restrict__ btbf,
    float* __restrict__ hp1, float* __restrict__ ss1, float* __restrict__ sd1,
    u64* __restrict__ maskN64, float* __restrict__ cvec)
{
    __shared__ float tile[64][65];   // 16.6 KB (conv_w2 transpose)
    __shared__ float feat[2][FIN];
    __shared__ float red[4][5];
    int blk = blockIdx.x;
    int t = threadIdx.x;
    if (blk < 896) {
        // conv_word: float4 -> ushort4
        int idx4 = blk * 256 + t;
        float4 x = ((const float4*)wf)[idx4];
        ushort4 y;
        y.x = f2bf(x.x); y.y = f2bf(x.y); y.z = f2bf(x.z); y.w = f2bf(x.w);
        ((ushort4*)abf)[idx4] = y;
    } else if (blk < 1152) {
        // gat1_hp: 2 rows per block
        int n0 = (blk - 896) * 2;
        feat[0][t] = pf[n0 * FIN + t];
        feat[1][t] = pf[(n0 + 1) * FIN + t];
        __syncthreads();
        int h = t >> 5, o = t & 31;
        float acc0 = 0.f, acc1 = 0.f;
        const float* wcol = w1 + h * FIN * O1 + o;
        #pragma unroll 4
        for (int f = 0; f < FIN; f++) {
            float w = wcol[f * O1];
            acc0 += feat[0][f] * w;
            acc1 += feat[1][f] * w;
        }
        hp1[n0 * 256 + t] = acc0;
        hp1[(n0 + 1) * 256 + t] = acc1;
        float as = a_src1[h * O1 + o];
        float ad = a_dst1[h * O1 + o];
        float accs[2] = {acc0, acc1};
        #pragma unroll
        for (int i = 0; i < 2; i++) {
            float th = tanhf(accs[i]);
            float vs = th * as, vd = th * ad;
            #pragma unroll
            for (int off = 1; off < 32; off <<= 1) {
                vs += __shfl_xor(vs, off);
                vd += __shfl_xor(vd, off);
            }
            if (o == 0) { ss1[h * NP + n0 + i] = vs; sd1[h * NP + n0 + i] = vd; }
        }
    } else if (blk < 1280) {
        // conv_w2: LDS-tiled transpose [h][f][o] -> bf16 [h][o][f], coalesced both ways
        int blk2 = blk - 1152;
        int h = blk2 >> 4;
        int f0 = ((blk2 >> 2) & 3) * 64;
        int o0 = (blk2 & 3) * 64;
        #pragma unroll
        for (int rr = 0; rr < 16; rr++) {
            int f = rr * 4 + (t >> 6);
            int o = t & 63;
            tile[f][o] = w2[((size_t)(h * FIN + f0 + f)) * O2 + o0 + o];
        }
        __syncthreads();
        #pragma unroll
        for (int rr = 0; rr < 16; rr++) {
            int o = rr * 4 + (t >> 6);
            int f = t & 63;
            btbf[((size_t)(h * O2 + o0 + o)) * FIN + f0 + f] = f2bf(tile[f][o]);
        }
    } else if (blk < 2176) {
        // pack_adj -> n-lane orientation: maskN64[ngrp(56)][m(4096)],
        // bit (n&63) of word = wp_adj[n][m] != 0.  One 64x64 tile per wave:
        // lane l owns column m = mgrp*64+l, iterates 64 rows (coalesced 256B/iter).
        int w = t >> 6, l = t & 63;
        int tid = (blk - 1280) * 4 + w;     // 0..3583
        int ngrp = tid >> 6;                // 0..55
        int mgrp = tid & 63;                // 0..63
        const int* base = wp_adj + (size_t)(ngrp * 64) * NT + mgrp * 64 + l;
        unsigned lo = 0, hi = 0;
        #pragma unroll 8
        for (int j = 0; j < 32; j++)
            lo |= (base[(size_t)j * NT] != 0 ? 1u : 0u) << j;
        #pragma unroll 8
        for (int j = 0; j < 32; j++)
            hi |= (base[(size_t)(j + 32) * NT] != 0 ? 1u : 0u) << j;
        maskN64[(size_t)ngrp * NT + mgrp * 64 + l] = ((u64)hi << 32) | lo;
    } else {
        // cvec: c[j] = b2 . W_fc[:,j]
        float v[5];
        #pragma unroll
        for (int j = 0; j < 5; j++) v[j] = b2[t] * W_fc[t * 5 + j];
        #pragma unroll
        for (int off = 1; off < 64; off <<= 1)
            #pragma unroll
            for (int j = 0; j < 5; j++) v[j] += __shfl_xor(v[j], off);
        int w = t >> 6, l = t & 63;
        if (l == 0) { for (int j = 0; j < 5; j++) red[w][j] = v[j]; }
        __syncthreads();
        if (t == 0)
            for (int j = 0; j < 5; j++) cvec[j] = red[0][j] + red[1][j] + red[2][j] + red[3][j];
    }
}

// ---- GAT1 attention: 2 query rows per block (256 blocks), deep-unrolled hp1 loop ----
__global__ __launch_bounds__(256) void k_gat1_attn(
    const int* __restrict__ adj, const float* __restrict__ hp1,
    const float* __restrict__ ss1, const float* __restrict__ sd1,
    const float* __restrict__ b1, unsigned short* __restrict__ abf)
{
    __shared__ float p[2][H1][NP];   // 32 KB
    __shared__ float den[2][H1];
    int t = threadIdx.x;
    int n0 = blockIdx.x * 2;
    for (int rr = 0; rr < 32; rr++) {
        int idx = rr * 256 + t;       // i(1) h(3) m(9)
        int i = idx >> 12, h = (idx >> 9) & 7, m = idx & 511;
        float a = adj[(n0 + i) * NP + m] > 0 ? 1.0f : 0.0f;
        float e = ss1[h * NP + n0 + i] + sd1[h * NP + m];
        e = fmaxf(e, NEG * e);
        p[i][h][m] = a * __expf(e);
    }
    __syncthreads();
    int w = t >> 6, l = t & 63;
    {
        int i = w & 1;
        #pragma unroll
        for (int hh = 0; hh < 4; hh++) {
            int h = (w >> 1) * 4 + hh;
            float s = 0;
            #pragma unroll
            for (int q = 0; q < 8; q++) s += p[i][h][l + 64 * q];
            #pragma unroll
            for (int off = 1; off < 64; off <<= 1) s += __shfl_xor(s, off);
            if (l == 0) den[i][h] = s;
        }
    }
    __syncthreads();
    int h = t >> 5, o = t & 31;
    float a0a = 0.f, a0b = 0.f, a1a = 0.f, a1b = 0.f;
    #pragma unroll 8
    for (int m = 0; m < NP; m += 2) {
        float v0 = hp1[m * 256 + t];
        float v1 = hp1[(m + 1) * 256 + t];
        a0a += p[0][h][m] * v0;
        a1a += p[1][h][m] * v0;
        a0b += p[0][h][m + 1] * v1;
        a1b += p[1][h][m + 1] * v1;
    }
    float acc[2] = {a0a + a0b, a1a + a1b};
    float bo = b1[o];
    #pragma unroll
    for (int i = 0; i < 2; i++) {
        float r = acc[i] / den[i][h] + bo;
        r = r > 0.f ? r : expm1f(r);   // elu
        abf[(NW + n0 + i) * FIN + t] = f2bf(r);
    }
}

// ---- hp2 GEMM: A-tile (128 x full-K) staged in LDS once; B streamed from L2 ----
// grid: b = mt(32)<<4 | h(8)<<1 | nt(2); block 256 thr, wave computes 64x64
__global__ __launch_bounds__(256) void k_gemm_hp2(
    const unsigned short* __restrict__ abf, const unsigned short* __restrict__ btbf,
    const float* __restrict__ a_src2, const float* __restrict__ a_dst2,
    const float* __restrict__ W_fc, float* __restrict__ gpart)
{
    __shared__ unsigned short As[128][264];   // 67.6 KB, +8-short pad (bank-safe)
    int b = blockIdx.x;
    int nt = b & 1, h = (b >> 1) & 7, mt = b >> 4;
    int t = threadIdx.x;
    int w = t >> 6, l = t & 63;
    int m0 = mt * 128;
    // stage A-tile: 16 rounds x 256 thr x 16B, coalesced
    {
        int row = t >> 5;            // 0..7 per round (+8 per round)
        int col8 = (t & 31) * 8;     // shorts
        #pragma unroll
        for (int u = 0; u < 16; u++)
            *(bf16x8*)(&As[u * 8 + row][col8]) =
                *(const bf16x8*)(abf + (size_t)(m0 + u * 8 + row) * FIN + col8);
    }
    __syncthreads();
    int am0 = (w >> 1) * 64;
    int n0 = nt * 128 + (w & 1) * 64;
    int lr = l & 15, lq = l >> 4;
    const unsigned short* bbase = btbf + h * O2 * FIN;
    f32x4 acc[4][4];
    #pragma unroll
    for (int i = 0; i < 4; i++)
        #pragma unroll
        for (int j = 0; j < 4; j++) acc[i][j] = (f32x4){0.f, 0.f, 0.f, 0.f};
    #pragma unroll
    for (int k = 0; k < FIN; k += 32) {
        bf16x8 a[4], bf[4];
        int kc = k + lq * 8;
        #pragma unroll
        for (int j = 0; j < 4; j++)
            bf[j] = *(const bf16x8*)(bbase + (size_t)(n0 + j * 16 + lr) * FIN + kc);
        #pragma unroll
        for (int i = 0; i < 4; i++)
            a[i] = *(const bf16x8*)(&As[am0 + i * 16 + lr][kc]);
        #pragma unroll
        for (int i = 0; i < 4; i++)
            #pragma unroll
            for (int j = 0; j < 4; j++)
                acc[i][j] = __builtin_amdgcn_mfma_f32_16x16x32_bf16(a[i], bf[j], acc[i][j], 0, 0, 0);
    }
    int slice = nt * 2 + (w & 1);
    float as[4], ad[4], wfc[4][5];
    #pragma unroll
    for (int j = 0; j < 4; j++) {
        int col = n0 + j * 16 + lr;
        as[j] = a_src2[h * O2 + col];
        ad[j] = a_dst2[h * O2 + col];
        #pragma unroll
        for (int jj = 0; jj < 5; jj++) wfc[j][jj] = W_fc[col * 5 + jj];
    }
    float* base = gpart + ((size_t)h * 4 + slice) * NT * 8;
    #pragma unroll
    for (int i = 0; i < 4; i++) {
        #pragma unroll
        for (int r = 0; r < 4; r++) {
            float s[7] = {0,0,0,0,0,0,0};
            #pragma unroll
            for (int j = 0; j < 4; j++) {
                float x = acc[i][j][r];
                float th = fast_tanh(x);
                s[0] += th * as[j];
                s[1] += th * ad[j];
                #pragma unroll
                for (int jj = 0; jj < 5; jj++) s[2 + jj] += x * wfc[j][jj];
            }
            #pragma unroll
            for (int off = 1; off < 16; off <<= 1)
                #pragma unroll
                for (int q = 0; q < 7; q++) s[q] += __shfl_xor(s[q], off);
            if (lr == 0) {
                int m = m0 + am0 + i * 16 + lq * 4 + r;
                float* dst = base + (size_t)m * 8;
                #pragma unroll
                for (int q = 0; q < 7; q++) dst[q] = s[q];
            }
        }
    }
}

// ---- combine slices -> Etab/Eptab (query side) + T={F,Fp,1,g0,g1,g2,g3,g4} (key side) ----
__global__ __launch_bounds__(256) void k_comb_hp2(
    const float* __restrict__ gpart,
    float* __restrict__ Etab, float* __restrict__ Eptab, float* __restrict__ T)
{
    int idx = blockIdx.x * 256 + threadIdx.x;   // h*NT + m
    float s[7] = {0,0,0,0,0,0,0};
    #pragma unroll
    for (int sl = 0; sl < 4; sl++) {
        const float* p = gpart + (((size_t)(idx >> 12) * 4 + sl) * NT + (idx & (NT - 1))) * 8;
        #pragma unroll
        for (int q = 0; q < 7; q++) s[q] += p[q];
    }
    Etab[idx]  = __expf(s[0]);
    Eptab[idx] = __expf(NEG * s[0]);
    float4 t0 = {__expf(s[1]), __expf(NEG * s[1]), 1.0f, s[2]};
    float4 t1 = {s[3], s[4], s[5], s[6]};
    *(float4*)(T + (size_t)idx * 8)     = t0;
    *(float4*)(T + (size_t)idx * 8 + 4) = t1;
}

// ---- GAT2 attention, n-on-lanes orientation ----
// grid: b = q4(14)<<6 | h(8)<<3 | c8(8); wave = (ngrp=q4*4+w, h, m-chunk c8 of 512)
// lane l owns row n = ngrp*64+l; {E,Ep} loop-invariant per lane; per m: T pairs via
// imm-offset dwordx2 loads, mask u64 = lane-mask via s-pair cndmask (SMEM dbuf stream).
__global__ __launch_bounds__(256) void k_gat2_attn(
    const u64* __restrict__ maskN64, const float* __restrict__ Etab,
    const float* __restrict__ Eptab, const float* __restrict__ T,
    float* __restrict__ part)
{
    int t = threadIdx.x;
    int w = t >> 6, l = t & 63;
    int b = blockIdx.x;
    int c8 = b & 7;
    int h  = (b >> 3) & 7;
    // readfirstlane -> provably wave-uniform (SGPR) so the "s"-constrained SMEM
    // pointers below get scalar registers (round-4-proven pattern; r5 compile fix)
    int ngrp = __builtin_amdgcn_readfirstlane((b >> 6) * 4 + w);   // 0..55
    int n = ngrp * 64 + l;
    v2f eE = (v2f){ Etab[h * NT + n], Eptab[h * NT + n] };   // per-lane, loop-invariant
    v2f accA = (v2f){0.f, 0.f};   // {den, g0}
    v2f accB = (v2f){0.f, 0.f};   // {g1, g2}
    v2f accC = (v2f){0.f, 0.f};   // {g3, g4}
    const float* Tb = T + ((size_t)h * NT + c8 * 512) * 8;
    const u64* mrow = maskN64 + (size_t)ngrp * NT + c8 * 512;
    // SMEM mask stream: 8 m per s_load_dwordx16, distance-1 double buffer (r4-proven)
    u32x16 mbufA, mbufB;
    asm volatile("s_load_dwordx16 %0, %1, 0x0" : "=s"(mbufA) : "s"(mrow));
    #define G2BODY(G, BUF)                                                            \
    {                                                                                 \
        const float* tg = Tb + (size_t)(G) * 64;                                      \
        _Pragma("unroll")                                                             \
        for (int k = 0; k < 8; k++) {                                                 \
            v2f ffp = *(const v2f*)(tg + k * 8);        /* {F, Fp}  */                \
            v2f g10 = *(const v2f*)(tg + k * 8 + 2);    /* {1, g0}  */                \
            v2f g21 = *(const v2f*)(tg + k * 8 + 4);    /* {g1, g2} */                \
            v2f g43 = *(const v2f*)(tg + k * 8 + 6);    /* {g3, g4} */                \
            u64 word = ((u64)BUF[2 * k + 1] << 32) | (u64)BUF[2 * k];                 \
            v2f pab;                                                                  \
            asm("v_pk_mul_f32 %0, %1, %2" : "=v"(pab) : "v"(ffp), "v"(eE));           \
            float pp0 = fmaxf(pab.x, pab.y);            /* exp(leaky(ss+sd)) */       \
            float ppl, pph;                                                           \
            asm("v_cndmask_b32 %0, 0, %1, %2" : "=v"(ppl) : "v"(pp0), "s"(word));     \
            asm("v_cndmask_b32 %0, 0, %1, %2" : "=v"(pph) : "v"(pp0), "s"(word));     \
            v2f ppv = (v2f){ppl, pph};                                                \
            asm("v_pk_fma_f32 %0, %1, %2, %0" : "+v"(accA) : "v"(ppv), "v"(g10));     \
            asm("v_pk_fma_f32 %0, %1, %2, %0" : "+v"(accB) : "v"(ppv), "v"(g21));     \
            asm("v_pk_fma_f32 %0, %1, %2, %0" : "+v"(accC) : "v"(ppv), "v"(g43));     \
        }                                                                             \
    }
    for (int g = 0; g < 64; g += 2) {
        asm volatile("s_waitcnt lgkmcnt(0)");
        __builtin_amdgcn_sched_barrier(0);
        {   // prefetch masks for group g+1 (flight = one 8-m body)
            const u64* mp = mrow + (size_t)(g + 1) * 8;
            asm volatile("s_load_dwordx16 %0, %1, 0x0" : "=s"(mbufB) : "s"(mp));
        }
        G2BODY(g, mbufA)
        asm volatile("s_waitcnt lgkmcnt(0)");
        __builtin_amdgcn_sched_barrier(0);
        {   // prefetch masks for group g+2 (clamped at tail: reload group 0, unused)
            const u64* mp = mrow + (size_t)((g + 2) & 63) * 8;
            asm volatile("s_load_dwordx16 %0, %1, 0x0" : "=s"(mbufA) : "s"(mp));
        }
        G2BODY(g + 1, mbufB)
    }
    #undef G2BODY
    // 6 coalesced stores; part6[k in 0..5][c8][h][n], k: 0=den, 1..5=g0..g4
    part[((size_t)(0 * 8 + c8) * 8 + h) * NW + n] = accA.x;
    part[((size_t)(1 * 8 + c8) * 8 + h) * NW + n] = accA.y;
    part[((size_t)(2 * 8 + c8) * 8 + h) * NW + n] = accB.x;
    part[((size_t)(3 * 8 + c8) * 8 + h) * NW + n] = accB.y;
    part[((size_t)(4 * 8 + c8) * 8 + h) * NW + n] = accC.x;
    part[((size_t)(5 * 8 + c8) * 8 + h) * NW + n] = accC.y;
}

// ---- combine chunks(8) + heads -> hf[n][5] ----
__global__ __launch_bounds__(256) void k_gat2_comb(const float* __restrict__ part,
                                                   float* __restrict__ hf) {
    int idx = blockIdx.x * 256 + threadIdx.x;  // n*8 + h
    int n = idx >> 3, h = idx & 7;
    float s[6] = {0, 0, 0, 0, 0, 0};
    #pragma unroll
    for (int c = 0; c < 8; c++)
        #pragma unroll
        for (int k = 0; k < 6; k++)
            s[k] += part[((size_t)(k * 8 + c) * 8 + h) * NW + n];
    float inv = 1.0f / (s[0] * 8.0f);
    float v[5];
    #pragma unroll
    for (int j = 0; j < 5; j++) v[j] = s[1 + j] * inv;
    #pragma unroll
    for (int off = 1; off < 8; off <<= 1)
        #pragma unroll
        for (int j = 0; j < 5; j++) v[j] += __shfl_xor(v[j], off);
    if (h == 0) {
        #pragma unroll
        for (int j = 0; j < 5; j++) hf[n * 5 + j] = v[j];
    }
}

// ---- out[b][j] = (input[b].hf[:,j]) / sum(input[b]) + c[j] + b_fc[j] ----
__global__ __launch_bounds__(256) void k_final(
    const float* __restrict__ input, const float* __restrict__ hf,
    const float* __restrict__ cvec, const float* __restrict__ b_fc,
    float* __restrict__ out)
{
    int b = blockIdx.x, t = threadIdx.x;
    const float4* row4 = (const float4*)(input + (size_t)b * NW);
    const float4* hf4 = (const float4*)hf;
    float s = 0.f, a[5] = {0.f, 0.f, 0.f, 0.f, 0.f};
    for (int idx = t; idx < NW / 4; idx += 256) {
        float4 x = row4[idx];
        float f[20];
        #pragma unroll
        for (int q = 0; q < 5; q++) *(float4*)(f + 4 * q) = hf4[idx * 5 + q];
        s += x.x + x.y + x.z + x.w;
        #pragma unroll
        for (int j = 0; j < 5; j++)
            a[j] += x.x * f[j] + x.y * f[5 + j] + x.z * f[10 + j] + x.w * f[15 + j];
    }
    #pragma unroll
    for (int off = 1; off < 64; off <<= 1) {
        s += __shfl_xor(s, off);
        #pragma unroll
        for (int j = 0; j < 5; j++) a[j] += __shfl_xor(a[j], off);
    }
    __shared__ float red[4][6];
    int w = t >> 6, l = t & 63;
    if (l == 0) { red[w][0] = s; for (int j = 0; j < 5; j++) red[w][j + 1] = a[j]; }
    __syncthreads();
    if (t < 5) {
        float st = red[0][0] + red[1][0] + red[2][0] + red[3][0];
        float aj = red[0][t + 1] + red[1][t + 1] + red[2][t + 1] + red[3][t + 1];
        out[b * 5 + t] = aj / st + cvec[t] + b_fc[t];
    }
}

extern "C" void kernel_launch(void* const* d_in, const int* in_sizes, int n_in,
                              void* d_out, int out_size, void* d_ws, size_t ws_size,
                              hipStream_t stream) {
    const float* input   = (const float*)d_in[0];
    const float* pf      = (const float*)d_in[1];
    const float* wf      = (const float*)d_in[2];
    const float* w1      = (const float*)d_in[3];
    const float* a_src1  = (const float*)d_in[4];
    const float* a_dst1  = (const float*)d_in[5];
    const float* b1      = (const float*)d_in[6];
    const float* w2      = (const float*)d_in[7];
    const float* a_src2  = (const float*)d_in[8];
    const float* a_dst2  = (const float*)d_in[9];
    const float* b2      = (const float*)d_in[10];
    const float* W_fc    = (const float*)d_in[11];
    const float* b_fc    = (const float*)d_in[12];
    const int* pern_adj  = (const int*)d_in[13];
    const int* wp_adj    = (const int*)d_in[14];
    float* out = (float*)d_out;

    char* ws = (char*)d_ws;
    unsigned short* abf    = (unsigned short*)(ws);            // 2 MB
    unsigned short* btbf   = (unsigned short*)(ws + 2097152);  // 1 MB
    float*          hp1    = (float*)(ws + 3145728);           // 512 KB
    float*          ss1    = (float*)(ws + 3670016);           // 16 KB
    float*          sd1    = (float*)(ws + 3686400);           // 16 KB
    float*          Etab   = (float*)(ws + 3833856);           // 128 KB
    float*          Eptab  = (float*)(ws + 3964928);           // 128 KB
    float*          T      = (float*)(ws + 4096000);           // 1 MB
    float*          hf     = (float*)(ws + 5144576);           // 70 KB
    float*          cvec   = (float*)(ws + 5216256);           // 64 B
    u64*            maskN64= (u64*)(ws + 5216512);             // 1.75 MB
    float*          gpart  = (float*)(ws + 7051520);           // 4 MB
    float*          part   = (float*)(ws + 11245824);          // 5.5 MB used

    k_prep<<<2177, 256, 0, stream>>>(wf, pf, w1, a_src1, a_dst1, w2, b2, W_fc,
                                     wp_adj, abf, btbf, hp1, ss1, sd1, maskN64, cvec);
    k_gat1_attn<<<256, 256, 0, stream>>>(pern_adj, hp1, ss1, sd1, b1, abf);
    k_gemm_hp2<<<512, 256, 0, stream>>>(abf, btbf, a_src2, a_dst2, W_fc, gpart);
    k_comb_hp2<<<128, 256, 0, stream>>>(gpart, Etab, Eptab, T);
    k_gat2_attn<<<896, 256, 0, stream>>>(maskN64, Etab, Eptab, T, part);
    k_gat2_comb<<<112, 256, 0, stream>>>(part, hf);
    k_final<<<1024, 256, 0, stream>>>(input, hf, cvec, b_fc, out);
}

// Round 7
// 240.704 us; speedup vs baseline: 1.1653x; 1.1653x over previous
//
#include <hip/hip_runtime.h>
#include <hip/hip_bf16.h>
#include <math.h>

#define NP 512
#define NW 3584
#define NT 4096
#define FIN 256
#define H1 8
#define O1 32
#define H2 8
#define O2 256
#define NEG 0.2f

typedef __attribute__((ext_vector_type(8))) short bf16x8;
typedef __attribute__((ext_vector_type(4))) float f32x4;
typedef __attribute__((ext_vector_type(2))) float v2f;
typedef __attribute__((ext_vector_type(16))) unsigned int u32x16;
typedef unsigned long long u64;

__device__ __forceinline__ unsigned short f2bf(float f) {
    unsigned u = __float_as_uint(f);
    unsigned r = (u + 0x7FFF + ((u >> 16) & 1)) >> 16;
    return (unsigned short)r;
}

__device__ __forceinline__ float fast_tanh(float x) {
    float ex = __expf(2.0f * x);
    return 1.0f - 2.0f / (ex + 1.0f);   // saturates to +-1
}

// ===== fused prep: conv_word | gat1_hp | conv_w2(transpose) | pack_adj(u64-T) | cvec
// grid = 896 + 256 + 128 + 896 + 1 = 2177 blocks of 256
__global__ __launch_bounds__(256) void k_prep(
    const float* __restrict__ wf, const float* __restrict__ pf,
    const float* __restrict__ w1, const float* __restrict__ a_src1,
    const float* __restrict__ a_dst1, const float* __restrict__ w2,
    const float* __restrict__ b2, const float* __restrict__ W_fc,
    const int* __restrict__ wp_adj,
    unsigned short* __restrict__ abf, unsigned short* __restrict__ btbf,
    float* __restrict__ hp1, float* __restrict__ ss1, float* __restrict__ sd1,
    u64* __restrict__ maskT64, float* __restrict__ cvec)
{
    __shared__ float tile[64][65];   // 16.6 KB (conv_w2 transpose)
    __shared__ float feat[2][FIN];
    __shared__ float red[4][5];
    int blk = blockIdx.x;
    int t = threadIdx.x;
    if (blk < 896) {
        // conv_word: float4 -> ushort4
        int idx4 = blk * 256 + t;
        float4 x = ((const float4*)wf)[idx4];
        ushort4 y;
        y.x = f2bf(x.x); y.y = f2bf(x.y); y.z = f2bf(x.z); y.w = f2bf(x.w);
        ((ushort4*)abf)[idx4] = y;
    } else if (blk < 1152) {
        // gat1_hp: 2 rows per block
        int n0 = (blk - 896) * 2;
        feat[0][t] = pf[n0 * FIN + t];
        feat[1][t] = pf[(n0 + 1) * FIN + t];
        __syncthreads();
        int h = t >> 5, o = t & 31;
        float acc0 = 0.f, acc1 = 0.f;
        const float* wcol = w1 + h * FIN * O1 + o;
        #pragma unroll 4
        for (int f = 0; f < FIN; f++) {
            float w = wcol[f * O1];
            acc0 += feat[0][f] * w;
            acc1 += feat[1][f] * w;
        }
        hp1[n0 * 256 + t] = acc0;
        hp1[(n0 + 1) * 256 + t] = acc1;
        float as = a_src1[h * O1 + o];
        float ad = a_dst1[h * O1 + o];
        float accs[2] = {acc0, acc1};
        #pragma unroll
        for (int i = 0; i < 2; i++) {
            float th = tanhf(accs[i]);
            float vs = th * as, vd = th * ad;
            #pragma unroll
            for (int off = 1; off < 32; off <<= 1) {
                vs += __shfl_xor(vs, off);
                vd += __shfl_xor(vd, off);
            }
            if (o == 0) { ss1[h * NP + n0 + i] = vs; sd1[h * NP + n0 + i] = vd; }
        }
    } else if (blk < 1280) {
        // conv_w2: LDS-tiled transpose [h][f][o] -> bf16 [h][o][f], coalesced both ways
        int blk2 = blk - 1152;
        int h = blk2 >> 4;
        int f0 = ((blk2 >> 2) & 3) * 64;
        int o0 = (blk2 & 3) * 64;
        #pragma unroll
        for (int rr = 0; rr < 16; rr++) {
            int f = rr * 4 + (t >> 6);
            int o = t & 63;
            tile[f][o] = w2[((size_t)(h * FIN + f0 + f)) * O2 + o0 + o];
        }
        __syncthreads();
        #pragma unroll
        for (int rr = 0; rr < 16; rr++) {
            int o = rr * 4 + (t >> 6);
            int f = t & 63;
            btbf[((size_t)(h * O2 + o0 + o)) * FIN + f0 + f] = f2bf(tile[f][o]);
        }
    } else if (blk < 2176) {
        // pack_adj -> u64 TRANSPOSED: maskT64[qw(64)][row(3584)]
        int w = t >> 6, l = t & 63;
        int r = (blk - 1280) * 4 + w;
        const int4* row = (const int4*)(wp_adj + (size_t)r * NT);
        for (int c4 = 0; c4 < 16; c4++) {
            int4 x = row[c4 * 64 + l];
            u64 nib = (u64)((x.x != 0 ? 1 : 0) | (x.y != 0 ? 2 : 0) |
                            (x.z != 0 ? 4 : 0) | (x.w != 0 ? 8 : 0));
            u64 v = nib << (4 * (l & 15));
            v |= __shfl_xor(v, 1);
            v |= __shfl_xor(v, 2);
            v |= __shfl_xor(v, 4);
            v |= __shfl_xor(v, 8);
            if ((l & 15) == 0) {
                int qw = c4 * 4 + (l >> 4);    // u64 column-qword index 0..63
                maskT64[(size_t)qw * NW + r] = v;
            }
        }
    } else {
        // cvec: c[j] = b2 . W_fc[:,j]
        float v[5];
        #pragma unroll
        for (int j = 0; j < 5; j++) v[j] = b2[t] * W_fc[t * 5 + j];
        #pragma unroll
        for (int off = 1; off < 64; off <<= 1)
            #pragma unroll
            for (int j = 0; j < 5; j++) v[j] += __shfl_xor(v[j], off);
        int w = t >> 6, l = t & 63;
        if (l == 0) { for (int j = 0; j < 5; j++) red[w][j] = v[j]; }
        __syncthreads();
        if (t == 0)
            for (int j = 0; j < 5; j++) cvec[j] = red[0][j] + red[1][j] + red[2][j] + red[3][j];
    }
}

// ---- GAT1 attention: 1 query row per block (512 blocks) for 2x occupancy ----
// (round-7 change: was 2 rows / 256 blocks = 1 wave/SIMD, zero TLP for the
//  latency-exposed hp1 L2 stream; same accumulation pairing -> bit-identical)
__global__ __launch_bounds__(256) void k_gat1_attn(
    const int* __restrict__ adj, const float* __restrict__ hp1,
    const float* __restrict__ ss1, const float* __restrict__ sd1,
    const float* __restrict__ b1, unsigned short* __restrict__ abf)
{
    __shared__ float p[H1][NP];   // 16 KB
    __shared__ float den[H1];
    int t = threadIdx.x;
    int n0 = blockIdx.x;
    #pragma unroll
    for (int rr = 0; rr < 16; rr++) {
        int idx = rr * 256 + t;       // h(3) m(9)
        int h = idx >> 9, m = idx & 511;
        float a = adj[n0 * NP + m] > 0 ? 1.0f : 0.0f;
        float e = ss1[h * NP + n0] + sd1[h * NP + m];
        e = fmaxf(e, NEG * e);
        p[h][m] = a * __expf(e);
    }
    __syncthreads();
    int w = t >> 6, l = t & 63;
    #pragma unroll
    for (int hh = 0; hh < 2; hh++) {
        int h = w * 2 + hh;
        float s = 0;
        #pragma unroll
        for (int q = 0; q < 8; q++) s += p[h][l + 64 * q];
        #pragma unroll
        for (int off = 1; off < 64; off <<= 1) s += __shfl_xor(s, off);
        if (l == 0) den[h] = s;
    }
    __syncthreads();
    int h = t >> 5, o = t & 31;
    float a0 = 0.f, a1 = 0.f;
    #pragma unroll 8
    for (int m = 0; m < NP; m += 2) {
        a0 += p[h][m] * hp1[m * 256 + t];
        a1 += p[h][m + 1] * hp1[(m + 1) * 256 + t];
    }
    float r = (a0 + a1) / den[h] + b1[o];
    r = r > 0.f ? r : expm1f(r);   // elu
    abf[(NW + n0) * FIN + t] = f2bf(r);
}

// ---- hp2 GEMM: A-tile (128 x full-K) staged in LDS once; B streamed from L2 ----
// grid: b = mt(32)<<4 | h(8)<<1 | nt(2); block 256 thr, wave computes 64x64
__global__ __launch_bounds__(256) void k_gemm_hp2(
    const unsigned short* __restrict__ abf, const unsigned short* __restrict__ btbf,
    const float* __restrict__ a_src2, const float* __restrict__ a_dst2,
    const float* __restrict__ W_fc, float* __restrict__ gpart)
{
    __shared__ unsigned short As[128][264];   // 67.6 KB, +8-short pad (bank-safe)
    int b = blockIdx.x;
    int nt = b & 1, h = (b >> 1) & 7, mt = b >> 4;
    int t = threadIdx.x;
    int w = t >> 6, l = t & 63;
    int m0 = mt * 128;
    // stage A-tile: 16 rounds x 256 thr x 16B, coalesced
    {
        int row = t >> 5;            // 0..7 per round (+8 per round)
        int col8 = (t & 31) * 8;     // shorts
        #pragma unroll
        for (int u = 0; u < 16; u++)
            *(bf16x8*)(&As[u * 8 + row][col8]) =
                *(const bf16x8*)(abf + (size_t)(m0 + u * 8 + row) * FIN + col8);
    }
    __syncthreads();
    int am0 = (w >> 1) * 64;
    int n0 = nt * 128 + (w & 1) * 64;
    int lr = l & 15, lq = l >> 4;
    const unsigned short* bbase = btbf + h * O2 * FIN;
    f32x4 acc[4][4];
    #pragma unroll
    for (int i = 0; i < 4; i++)
        #pragma unroll
        for (int j = 0; j < 4; j++) acc[i][j] = (f32x4){0.f, 0.f, 0.f, 0.f};
    #pragma unroll
    for (int k = 0; k < FIN; k += 32) {
        bf16x8 a[4], bf[4];
        int kc = k + lq * 8;
        #pragma unroll
        for (int j = 0; j < 4; j++)
            bf[j] = *(const bf16x8*)(bbase + (size_t)(n0 + j * 16 + lr) * FIN + kc);
        #pragma unroll
        for (int i = 0; i < 4; i++)
            a[i] = *(const bf16x8*)(&As[am0 + i * 16 + lr][kc]);
        #pragma unroll
        for (int i = 0; i < 4; i++)
            #pragma unroll
            for (int j = 0; j < 4; j++)
                acc[i][j] = __builtin_amdgcn_mfma_f32_16x16x32_bf16(a[i], bf[j], acc[i][j], 0, 0, 0);
    }
    int slice = nt * 2 + (w & 1);
    float as[4], ad[4], wfc[4][5];
    #pragma unroll
    for (int j = 0; j < 4; j++) {
        int col = n0 + j * 16 + lr;
        as[j] = a_src2[h * O2 + col];
        ad[j] = a_dst2[h * O2 + col];
        #pragma unroll
        for (int jj = 0; jj < 5; jj++) wfc[j][jj] = W_fc[col * 5 + jj];
    }
    float* base = gpart + ((size_t)h * 4 + slice) * NT * 8;
    #pragma unroll
    for (int i = 0; i < 4; i++) {
        #pragma unroll
        for (int r = 0; r < 4; r++) {
            float s[7] = {0,0,0,0,0,0,0};
            #pragma unroll
            for (int j = 0; j < 4; j++) {
                float x = acc[i][j][r];
                float th = fast_tanh(x);
                s[0] += th * as[j];
                s[1] += th * ad[j];
                #pragma unroll
                for (int jj = 0; jj < 5; jj++) s[2 + jj] += x * wfc[j][jj];
            }
            #pragma unroll
            for (int off = 1; off < 16; off <<= 1)
                #pragma unroll
                for (int q = 0; q < 7; q++) s[q] += __shfl_xor(s[q], off);
            if (lr == 0) {
                int m = m0 + am0 + i * 16 + lq * 4 + r;
                float* dst = base + (size_t)m * 8;
                #pragma unroll
                for (int q = 0; q < 7; q++) dst[q] = s[q];
            }
        }
    }
}

// ---- combine slices -> Etab/Eptab (query side) + T={F,Fp,1,g0,g1,g2,g3,g4} (key side) ----
__global__ __launch_bounds__(256) void k_comb_hp2(
    const float* __restrict__ gpart,
    float* __restrict__ Etab, float* __restrict__ Eptab, float* __restrict__ T)
{
    int idx = blockIdx.x * 256 + threadIdx.x;   // h*NT + m
    float s[7] = {0,0,0,0,0,0,0};
    #pragma unroll
    for (int sl = 0; sl < 4; sl++) {
        const float* p = gpart + (((size_t)(idx >> 12) * 4 + sl) * NT + (idx & (NT - 1))) * 8;
        #pragma unroll
        for (int q = 0; q < 7; q++) s[q] += p[q];
    }
    Etab[idx]  = __expf(s[0]);
    Eptab[idx] = __expf(NEG * s[0]);
    float4 t0 = {__expf(s[1]), __expf(NEG * s[1]), 1.0f, s[2]};
    float4 t1 = {s[3], s[4], s[5], s[6]};
    *(float4*)(T + (size_t)idx * 8)     = t0;
    *(float4*)(T + (size_t)idx * 8 + 4) = t1;
}

// ---- GAT2 attention: distance-1 double-buffered s_load_dwordx16 masks, pk_fma accum ----
// grid: nb(112) x h(8) x c(2), 256 thr; wave owns 8 rows; lane owns m = c*2048+q*64+l
__global__ __launch_bounds__(256) void k_gat2_attn(
    const u64* __restrict__ maskT64, const float* __restrict__ Etab,
    const float* __restrict__ Eptab, const float* __restrict__ T,
    float* __restrict__ part)
{
    int t = threadIdx.x;
    int w = t >> 6, l = t & 63;
    int b = blockIdx.x;
    int nb = b % 112;
    int h  = (b / 112) & 7;
    int c  = b / 896;
    int n0 = __builtin_amdgcn_readfirstlane(nb * 32 + w * 8);  // scalar row base
    // per-row {E, Ep} pairs in VGPRs (wave-uniform value, frees SGPRs for mask bufs)
    v2f ev[8];
    #pragma unroll
    for (int i = 0; i < 8; i++) {
        int r = h * NT + n0 + i;
        ev[i] = (v2f){Etab[r], Eptab[r]};
    }
    // pair accumulators: accA={den,g0}, accB={g1,g2}, accC={g3,g4}
    v2f accA[8], accB[8], accC[8];
    #pragma unroll
    for (int i = 0; i < 8; i++) {
        accA[i] = (v2f){0.f, 0.f};
        accB[i] = (v2f){0.f, 0.f};
        accC[i] = (v2f){0.f, 0.f};
    }
    const float* Th = T + ((size_t)h * NT + c * 2048) * 8;
    const u64* mbase = maskT64 + (size_t)(c * 32) * NW + n0;   // wave-uniform
    // SMEM mask double-buffer. Each q needs 8 row-masks = 64 contiguous bytes at a
    // wave-uniform address -> one s_load_dwordx16. Distance-1: the wait at the top of
    // each half-body drains a load issued one half-body (~350 cy wall) earlier.
    // SMEM returns are unordered -> only lgkmcnt(0) is safe; sched_barrier(0) after the
    // wait (rule #18) stops the compiler hoisting consumers above it.
    u32x16 bufA, bufB;
    asm volatile("s_load_dwordx16 %0, %1, 0x0" : "=s"(bufA) : "s"(mbase));
    #define GAT2_BODY(QQ, BUF)                                                         \
    {                                                                                  \
        const float* tp = Th + (size_t)((QQ) * 64 + l) * 8;                            \
        f32x4 t0 = *(const f32x4*)tp;        /* {F, Fp, 1, g0} */                      \
        f32x4 t1 = *(const f32x4*)(tp + 4);  /* {g1, g2, g3, g4} */                    \
        v2f ffp = {t0.x, t0.y};                                                        \
        v2f m0  = {t0.z, t0.w};                                                        \
        v2f m1  = {t1.x, t1.y};                                                        \
        v2f m2  = {t1.z, t1.w};                                                        \
        _Pragma("unroll")                                                              \
        for (int i = 0; i < 8; i++) {                                                  \
            u64 word = ((u64)BUF[2 * i + 1] << 32) | (u64)BUF[2 * i];                  \
            v2f pab;                                                                   \
            asm("v_pk_mul_f32 %0, %1, %2" : "=v"(pab) : "v"(ffp), "v"(ev[i]));         \
            float pp0 = fmaxf(pab.x, pab.y);   /* exp(leaky(ss+sd)) */                 \
            float ppl, pph;                                                            \
            asm("v_cndmask_b32 %0, 0, %1, %2" : "=v"(ppl) : "v"(pp0), "s"(word));      \
            asm("v_cndmask_b32 %0, 0, %1, %2" : "=v"(pph) : "v"(pp0), "s"(word));      \
            v2f ppv = {ppl, pph};                                                      \
            asm("v_pk_fma_f32 %0, %1, %2, %0" : "+v"(accA[i]) : "v"(ppv), "v"(m0));    \
            asm("v_pk_fma_f32 %0, %1, %2, %0" : "+v"(accB[i]) : "v"(ppv), "v"(m1));    \
            asm("v_pk_fma_f32 %0, %1, %2, %0" : "+v"(accC[i]) : "v"(ppv), "v"(m2));    \
        }                                                                              \
    }
    for (int q = 0; q < 32; q += 2) {
        asm volatile("s_waitcnt lgkmcnt(0)");
        __builtin_amdgcn_sched_barrier(0);
        {   // prefetch masks for q+1 (flight = body q)
            const u64* mp = mbase + (size_t)(q + 1) * NW;
            asm volatile("s_load_dwordx16 %0, %1, 0x0" : "=s"(bufB) : "s"(mp));
        }
        GAT2_BODY(q, bufA)
        asm volatile("s_waitcnt lgkmcnt(0)");
        __builtin_amdgcn_sched_barrier(0);
        {   // prefetch masks for q+2; clamp at the tail (q=30 -> reload row 0, unused)
            // so every SMEM load stays inside the maskT64 table
            int qn = (q + 2) & 31;
            const u64* mp = mbase + (size_t)qn * NW;
            asm volatile("s_load_dwordx16 %0, %1, 0x0" : "=s"(bufA) : "s"(mp));
        }
        GAT2_BODY(q + 1, bufB)
    }
    #undef GAT2_BODY
    #pragma unroll
    for (int i = 0; i < 8; i++) {
        float v[6] = {accA[i].x, accA[i].y, accB[i].x, accB[i].y, accC[i].x, accC[i].y};
        #pragma unroll
        for (int off = 1; off < 8; off <<= 1)
            #pragma unroll
            for (int k = 0; k < 6; k++) v[k] += __shfl_xor(v[k], off);
        if ((l & 7) == 0) {
            float* dst = part + ((((size_t)c * NW + n0 + i) * 8 + h) * 8 + (l >> 3)) * 8;
            #pragma unroll
            for (int k = 0; k < 6; k++) dst[k] = v[k];
        }
    }
}

// ---- combine chunks(2) x octet-partials(8) + heads -> hf[n][5] ----
__global__ __launch_bounds__(256) void k_gat2_comb(const float* __restrict__ part,
                                                   float* __restrict__ hf) {
    int idx = blockIdx.x * 256 + threadIdx.x;  // n*8 + h
    int n = idx >> 3, h = idx & 7;
    float den = 0, num[5] = {0,0,0,0,0};
    #pragma unroll
    for (int cc = 0; cc < 2; cc++) {
        #pragma unroll
        for (int s = 0; s < 8; s++) {
            const float* p = part + ((((size_t)cc * NW + n) * 8 + h) * 8 + s) * 8;
            float4 a = *(const float4*)p;
            float4 bq = *(const float4*)(p + 4);
            den += a.x;
            num[0] += a.y; num[1] += a.z; num[2] += a.w;
            num[3] += bq.x; num[4] += bq.y;
        }
    }
    float inv = 1.0f / (den * 8.0f);
    float v[5];
    #pragma unroll
    for (int j = 0; j < 5; j++) v[j] = num[j] * inv;
    #pragma unroll
    for (int off = 1; off < 8; off <<= 1)
        #pragma unroll
        for (int j = 0; j < 5; j++) v[j] += __shfl_xor(v[j], off);
    if (h == 0) {
        #pragma unroll
        for (int j = 0; j < 5; j++) hf[n * 5 + j] = v[j];
    }
}

// ---- out[b][j] = (input[b].hf[:,j]) / sum(input[b]) + c[j] + b_fc[j] ----
__global__ __launch_bounds__(256) void k_final(
    const float* __restrict__ input, const float* __restrict__ hf,
    const float* __restrict__ cvec, const float* __restrict__ b_fc,
    float* __restrict__ out)
{
    int b = blockIdx.x, t = threadIdx.x;
    const float4* row4 = (const float4*)(input + (size_t)b * NW);
    const float4* hf4 = (const float4*)hf;
    float s = 0.f, a[5] = {0.f, 0.f, 0.f, 0.f, 0.f};
    for (int idx = t; idx < NW / 4; idx += 256) {
        float4 x = row4[idx];
        float f[20];
        #pragma unroll
        for (int q = 0; q < 5; q++) *(float4*)(f + 4 * q) = hf4[idx * 5 + q];
        s += x.x + x.y + x.z + x.w;
        #pragma unroll
        for (int j = 0; j < 5; j++)
            a[j] += x.x * f[j] + x.y * f[5 + j] + x.z * f[10 + j] + x.w * f[15 + j];
    }
    #pragma unroll
    for (int off = 1; off < 64; off <<= 1) {
        s += __shfl_xor(s, off);
        #pragma unroll
        for (int j = 0; j < 5; j++) a[j] += __shfl_xor(a[j], off);
    }
    __shared__ float red[4][6];
    int w = t >> 6, l = t & 63;
    if (l == 0) { red[w][0] = s; for (int j = 0; j < 5; j++) red[w][j + 1] = a[j]; }
    __syncthreads();
    if (t < 5) {
        float st = red[0][0] + red[1][0] + red[2][0] + red[3][0];
        float aj = red[0][t + 1] + red[1][t + 1] + red[2][t + 1] + red[3][t + 1];
        out[b * 5 + t] = aj / st + cvec[t] + b_fc[t];
    }
}

extern "C" void kernel_launch(void* const* d_in, const int* in_sizes, int n_in,
                              void* d_out, int out_size, void* d_ws, size_t ws_size,
                              hipStream_t stream) {
    const float* input   = (const float*)d_in[0];
    const float* pf      = (const float*)d_in[1];
    const float* wf      = (const float*)d_in[2];
    const float* w1      = (const float*)d_in[3];
    const float* a_src1  = (const float*)d_in[4];
    const float* a_dst1  = (const float*)d_in[5];
    const float* b1      = (const float*)d_in[6];
    const float* w2      = (const float*)d_in[7];
    const float* a_src2  = (const float*)d_in[8];
    const float* a_dst2  = (const float*)d_in[9];
    const float* b2      = (const float*)d_in[10];
    const float* W_fc    = (const float*)d_in[11];
    const float* b_fc    = (const float*)d_in[12];
    const int* pern_adj  = (const int*)d_in[13];
    const int* wp_adj    = (const int*)d_in[14];
    float* out = (float*)d_out;

    char* ws = (char*)d_ws;
    unsigned short* abf    = (unsigned short*)(ws);            // 2 MB
    unsigned short* btbf   = (unsigned short*)(ws + 2097152);  // 1 MB
    float*          hp1    = (float*)(ws + 3145728);           // 512 KB
    float*          ss1    = (float*)(ws + 3670016);           // 16 KB
    float*          sd1    = (float*)(ws + 3686400);           // 16 KB
    float*          Etab   = (float*)(ws + 3833856);           // 128 KB
    float*          Eptab  = (float*)(ws + 3964928);           // 128 KB
    float*          T      = (float*)(ws + 4096000);           // 1 MB
    float*          hf     = (float*)(ws + 5144576);           // 70 KB
    float*          cvec   = (float*)(ws + 5216256);           // 64 B
    u64*            maskT64= (u64*)(ws + 5216512);             // 1.75 MB
    float*          gpart  = (float*)(ws + 7051520);           // 4 MB
    float*          part   = (float*)(ws + 11245824);          // 14.7 MB

    k_prep<<<2177, 256, 0, stream>>>(wf, pf, w1, a_src1, a_dst1, w2, b2, W_fc,
                                     wp_adj, abf, btbf, hp1, ss1, sd1, maskT64, cvec);
    k_gat1_attn<<<512, 256, 0, stream>>>(pern_adj, hp1, ss1, sd1, b1, abf);
    k_gemm_hp2<<<512, 256, 0, stream>>>(abf, btbf, a_src2, a_dst2, W_fc, gpart);
    k_comb_hp2<<<128, 256, 0, stream>>>(gpart, Etab, Eptab, T);
    k_gat2_attn<<<1792, 256, 0, stream>>>(maskT64, Etab, Eptab, T, part);
    k_gat2_comb<<<112, 256, 0, stream>>>(part, hf);
    k_final<<<1024, 256, 0, stream>>>(input, hf, cvec, b_fc, out);
}